// Round 19
// baseline (193.461 us; speedup 1.0000x reference)
//
#include <hip/hip_runtime.h>
#include <math.h>

#define NPTS 8192
#define NB   4
#define KNN  16
#define NC   64
#define NQ   (NB * NPTS)   // 32768 total queries
#define QPB  32            // queries per knn block (r19: was 64; grid x2 for TLP)
#define ECAP 20            // per-(wave,query) packed-entry capacity (E~2.7)
#define ILCAP 66           // per-query decoded survivor idx capacity (E~22)

// ---------------------------------------------------------------------------
// prep — unchanged (validated r18): 64-thread / 64-point blocks, grid 2048.
//  phase 0 (source pts): cand[b][m]=(x,y,z,|p|^2); GF[b][m][o]=(Gk,F2)
//  phase 1 (center pts): CF[b][n][o]=(Gc+bg, F1+bf)
// ---------------------------------------------------------------------------
__global__ __launch_bounds__(64) void prep_kernel(
    const float* __restrict__ xyz, const float* __restrict__ xyz_s,
    const float* __restrict__ fea, const float* __restrict__ fea_s,
    const float* __restrict__ Wg,  const float* __restrict__ bg,
    const float* __restrict__ Wf,  const float* __restrict__ bf,
    float4* __restrict__ cand, float2* __restrict__ GF, float2* __restrict__ CF)
{
    __shared__ float wt[64 * 64];
    __shared__ float gw[3 * 64];
    __shared__ float bias2[2 * 64];
    int tid   = threadIdx.x;
    int phase = blockIdx.x & 1;
    int g     = (blockIdx.x >> 1) * 64 + tid;
    int b     = g >> 13, m = g & (NPTS - 1);

    for (int i = tid; i < 4096; i += 64) {
        int o = i >> 6, c = i & 63;
        wt[c * 64 + o] = Wf[o * 128 + (phase ? c : 64 + c)];
    }
    for (int i = tid; i < 192; i += 64) {
        int d = i >> 6, o = i & 63;
        gw[d * 64 + o] = phase ? (Wg[o * 10 + 1 + d] + Wg[o * 10 + 7 + d])
                               : (Wg[o * 10 + 4 + d] - Wg[o * 10 + 7 + d]);
    }
    {
        bias2[tid]      = phase ? bg[tid] : 0.f;
        bias2[64 + tid] = phase ? bf[tid] : 0.f;
    }
    __syncthreads();

    const float* P = phase ? xyz : xyz_s;
    const float* F = phase ? fea : fea_s;
    float x = P[(b * 3 + 0) * NPTS + m];
    float y = P[(b * 3 + 1) * NPTS + m];
    float z = P[(b * 3 + 2) * NPTS + m];
    if (!phase) cand[b * NPTS + m] = make_float4(x, y, z, x * x + y * y + z * z);

    float acc[NC];
    #pragma unroll
    for (int o = 0; o < NC; o++) acc[o] = 0.f;
    for (int c = 0; c < NC; c++) {
        float v = F[(size_t)(b * NC + c) * NPTS + m];
        const float4* w4 = (const float4*)&wt[c * 64];
        #pragma unroll
        for (int o4 = 0; o4 < 16; o4++) {
            float4 w = w4[o4];
            acc[o4*4+0] = fmaf(w.x, v, acc[o4*4+0]);
            acc[o4*4+1] = fmaf(w.y, v, acc[o4*4+1]);
            acc[o4*4+2] = fmaf(w.z, v, acc[o4*4+2]);
            acc[o4*4+3] = fmaf(w.w, v, acc[o4*4+3]);
        }
    }
    float2* O = (phase ? CF : GF) + ((size_t)(b * NPTS + m)) * NC;
    #pragma unroll
    for (int o = 0; o < NC; o++) {
        float geo = fmaf(gw[o], x, fmaf(gw[64 + o], y, gw[128 + o] * z));
        O[o] = make_float2(geo + bias2[o], acc[o] + bias2[64 + o]);
    }
}

// ---------------------------------------------------------------------------
// knn_fused6 = r16/r18's knn_fused4 with QPB=32 (was 64), grid 1024.
// [r18 post-mortem: knn occupancy was GRID-limited — 512 blocks x 8 waves =
//  4096 waves on 8192 slots (50% cap, 30% measured); VALU work itself is
//  near-floor. Halving queries/block doubles the grid -> 4 blocks/CU = 8
//  waves/SIMD; per-block candidate residency (8192) and ALL arithmetic
//  unchanged; candidate prologue loads double chip-wide (FETCH 2.3->4.6MB,
//  trivial). LDS drops 59->30KB.]
// Wave w owns cands [1024w,1024(w+1)); lane owns c[s]=cb[w*1024+s*64+lane].
//  A: full 16-slot dual-chain lane max -> shfl_xor(1,2,4) -> 64 submaxima
//     (128-cand disjoint groups covering all 8192).
//  T: tau = 16th largest of 64 submaxima -> qt_lds[q].w; >=16 witnesses.
//  B: branch-free u16 mask filter (bit-identical fma), ONE ballot/query,
//     packed (lane<<16)|mask entries.
//  S: decode -> idx list (dead mxs row) -> batch-4 gather + u64 insert.
// Grid: NQ/QPB = 1024 blocks x 512 threads.
// ---------------------------------------------------------------------------
__global__ __launch_bounds__(512, 4) void knn_fused6(
    const float4* __restrict__ cand, const float* __restrict__ xyz,
    int* __restrict__ idxout)
{
    __shared__ float4 qt_lds[QPB];           // .w = tau after T
    __shared__ float  mxs[QPB][ILCAP];       // A/T: submaxima; S: idx list
    __shared__ unsigned int  el[8][QPB][ECAP];
    __shared__ unsigned char ecnt[8][QPB];

    int tid = threadIdx.x;
    int lane = tid & 63, w = tid >> 6;       // w in 0..7
    int bid = blockIdx.x;
    int b = bid >> 8;                        // 256 blocks per batch
    int qb = (bid & 255) * QPB;

    if (tid < QPB) {
        int q = qb + tid;
        float x = xyz[(b * 3 + 0) * NPTS + q];
        float y = xyz[(b * 3 + 1) * NPTS + q];
        float z = xyz[(b * 3 + 2) * NPTS + q];
        qt_lds[tid] = make_float4(2.f * x, 2.f * y, 2.f * z, 0.f);
    }

    const float4* cb = cand + b * NPTS;
    int cbase = (w << 10) + lane;            // lane's cands: cbase + s*64
    float4 c[16];
    #pragma unroll
    for (int s = 0; s < 16; s++) c[s] = cb[cbase + (s << 6)];
    // residency force (r15-validated): compiler cannot re-load from memory
    #pragma unroll
    for (int s = 0; s < 16; s++)
        asm volatile("" : "+v"(c[s].x), "+v"(c[s].y), "+v"(c[s].z), "+v"(c[s].w));
    __syncthreads();

    // ---- A: 64 submaxima per query (dual-chain lane max + 8-lane reduce) --
    for (int qi = 0; qi < QPB; ++qi) {
        float4 qt = qt_lds[qi];
        float M0 = -3.0e38f, M1 = -3.0e38f;
        #pragma unroll
        for (int s = 0; s < 16; s += 2) {
            float sc0 = fmaf(c[s].x, qt.x, fmaf(c[s].y, qt.y,
                        fmaf(c[s].z, qt.z, -c[s].w)));
            float sc1 = fmaf(c[s+1].x, qt.x, fmaf(c[s+1].y, qt.y,
                        fmaf(c[s+1].z, qt.z, -c[s+1].w)));
            M0 = fmaxf(M0, sc0);
            M1 = fmaxf(M1, sc1);
        }
        float gmx = fmaxf(M0, M1);
        gmx = fmaxf(gmx, __shfl_xor(gmx, 1));
        gmx = fmaxf(gmx, __shfl_xor(gmx, 2));
        gmx = fmaxf(gmx, __shfl_xor(gmx, 4));   // 8-lane group max
        if ((lane & 7) == 0) mxs[qi][(w << 3) + (lane >> 3)] = gmx;
    }
    __syncthreads();

    // ---- T: tau = 16th largest of 64 submaxima -> qt_lds[qq].w ----
    for (int qq = w * 4; qq < w * 4 + 4; ++qq) {
        float v = mxs[qq][lane];
        #pragma unroll
        for (int k = 2; k <= 64; k <<= 1) {
            #pragma unroll
            for (int j = k >> 1; j > 0; j >>= 1) {
                float o = __shfl_xor(v, j);
                bool up = ((lane & k) == 0);
                bool lower = ((lane & j) == 0);
                v = (up == lower) ? fminf(v, o) : fmaxf(v, o);
            }
        }
        float t = __shfl(v, 48);             // 16th largest (all lanes)
        if (lane == 0) qt_lds[qq].w = t;
    }
    __syncthreads();

    // ---- B: branch-free mask filter; ONE ballot per (wave,query) ----
    unsigned long long lmask = (1ull << lane) - 1ull;
    for (int qi = 0; qi < QPB; ++qi) {
        float4 qt = qt_lds[qi];              // .w = tau
        unsigned msk = 0;
        #pragma unroll
        for (int s = 0; s < 16; s++) {
            float sc = fmaf(c[s].x, qt.x, fmaf(c[s].y, qt.y,
                       fmaf(c[s].z, qt.z, -c[s].w)));
            msk |= (sc >= qt.w) ? (1u << s) : 0u;
        }
        unsigned long long m = __ballot(msk != 0u);
        if (msk) {
            unsigned pos = (unsigned)__popcll(m & lmask);
            if (pos < ECAP)
                el[w][qi][pos] = ((unsigned)lane << 16) | msk;
        }
        if (lane == 0) {
            unsigned tot = (unsigned)__popcll(m);
            ecnt[w][qi] = (unsigned char)(tot < ECAP ? tot : ECAP);
        }
    }
    __syncthreads();

    // ---- S: decode entries -> idx list (reuse mxs row), then top-16 ----
    if (tid < QPB) {
        int qi = tid;
        unsigned* il = (unsigned*)&mxs[qi][0];   // ILCAP u32 slots
        int cnt = 0;
        for (int w2 = 0; w2 < 8; w2++) {
            int cn = ecnt[w2][qi];
            for (int j = 0; j < cn; j++) {
                unsigned e = el[w2][qi][j];
                int base = (w2 << 10) + (int)(e >> 16);
                unsigned mk = e & 0xFFFFu;
                while (mk) {
                    int s = __builtin_ctz(mk);
                    mk &= mk - 1u;
                    if (cnt < ILCAP) il[cnt++] = (unsigned)(base + (s << 6));
                }
            }
        }

        float4 qt = qt_lds[qi];
        unsigned long long s16[KNN];
        #pragma unroll
        for (int j = 0; j < KNN; j++) s16[j] = 0ull;

        for (int j0 = 0; j0 < cnt; j0 += 4) {
            int li[4];
            float4 cd[4];
            #pragma unroll
            for (int t = 0; t < 4; t++) {
                int j = j0 + t;
                li[t] = (j < cnt) ? (int)il[j] : -1;
            }
            #pragma unroll
            for (int t = 0; t < 4; t++)
                if (li[t] >= 0) cd[t] = cb[li[t]];
            #pragma unroll
            for (int t = 0; t < 4; t++) {
                if (li[t] < 0) continue;
                float sc = fmaf(cd[t].x, qt.x, fmaf(cd[t].y, qt.y,
                           fmaf(cd[t].z, qt.z, -cd[t].w)));
                unsigned u = __float_as_uint(sc);
                u ^= (unsigned)((int)u >> 31) | 0x80000000u;
                unsigned long long key =
                    ((unsigned long long)u << 32) | (unsigned)(8191 - li[t]);
                if (key > s16[0]) {
                    bool cj = true;
                    #pragma unroll
                    for (int t2 = 0; t2 < KNN; t2++) {
                        bool cn2 = (t2 < KNN - 1) ? (key > s16[t2 + 1]) : false;
                        unsigned long long fv = cj ? key : s16[t2];
                        s16[t2] = cn2 ? s16[t2 + 1] : fv;
                        cj = cn2;
                    }
                }
            }
        }
        int* op = idxout + (((size_t)(b * NPTS + qb + qi)) << 4);
        #pragma unroll
        for (int j = 0; j < KNN; j++)
            op[j] = 8191 - (int)(s16[j] & 0xFFFFFFFFull);
    }
}

// ---------------------------------------------------------------------------
// fuse — unchanged (validated r2..r18):
// out[b][o][n] = max_k relu(CF.x + wd*d + GF.x) * relu(CF.y + GF.y)
// ---------------------------------------------------------------------------
__global__ __launch_bounds__(256) void fuse_kernel(
    const float* __restrict__ xyz, const float* __restrict__ Wg,
    const float4* __restrict__ cand, const float2* __restrict__ GF,
    const float2* __restrict__ CF, const int* __restrict__ idxb,
    float* __restrict__ out)
{
    __shared__ float tile[16 * 65];
    int tid = threadIdx.x;
    int o = tid & 63, w = tid >> 6;
    int b = blockIdx.x >> 9;
    int nt = (blockIdx.x & 511) << 4;
    float wd = Wg[o * 10];

    for (int i = 0; i < 4; i++) {
        int q = nt + w * 4 + i;
        size_t qb = (size_t)(b * NPTS + q);
        float qx = xyz[(b * 3 + 0) * NPTS + q];
        float qy = xyz[(b * 3 + 1) * NPTS + q];
        float qz = xyz[(b * 3 + 2) * NPTS + q];
        float2 cf = CF[qb * NC + o];
        const int* ip = idxb + qb * KNN;
        float r = 0.f;
        #pragma unroll 4
        for (int kk = 0; kk < KNN; kk++) {
            int mi = ip[kk];
            float4 c = cand[b * NPTS + mi];
            float dx = qx - c.x, dy = qy - c.y, dz = qz - c.z;
            float d = sqrtf(fmaf(dx, dx, fmaf(dy, dy, dz * dz)));
            float2 gf = GF[((size_t)(b * NPTS + mi)) * NC + o];
            float gpre = cf.x + fmaf(wd, d, gf.x);
            float fpre = cf.y + gf.y;
            r = fmaxf(r, fmaxf(gpre, 0.f) * fmaxf(fpre, 0.f));
        }
        tile[(w * 4 + i) * 65 + o] = r;
    }
    __syncthreads();
    int row = tid >> 2, cg = (tid & 3) * 4;
    float* orow = out + (size_t)(b * NC + row) * NPTS + nt + cg;
    #pragma unroll
    for (int j = 0; j < 4; j++) orow[j] = tile[(cg + j) * 65 + row];
}

extern "C" void kernel_launch(void* const* d_in, const int* in_sizes, int n_in,
                              void* d_out, int out_size, void* d_ws, size_t ws_size,
                              hipStream_t stream) {
    const float* xyz   = (const float*)d_in[0];
    const float* xyz_s = (const float*)d_in[1];
    const float* fea   = (const float*)d_in[2];
    const float* fea_s = (const float*)d_in[3];
    const float* Wg    = (const float*)d_in[4];
    const float* bg    = (const float*)d_in[5];
    const float* Wf    = (const float*)d_in[6];
    const float* bf    = (const float*)d_in[7];
    float* out = (float*)d_out;

    char* ws = (char*)d_ws;
    float4* cand = (float4*)ws;                 ws += (size_t)NQ * 16;      // 512 KB
    float2* GF   = (float2*)ws;                 ws += (size_t)NQ * NC * 8;  // 16.8 MB
    float2* CF   = (float2*)ws;                 ws += (size_t)NQ * NC * 8;  // 16.8 MB
    int*    idxb = (int*)ws;                                                // 2 MB

    // prep: 64-point / 64-thread blocks -> 2048 blocks = 8 blocks/CU
    prep_kernel<<<(NQ / 64) * 2, 64, 0, stream>>>(
        xyz, xyz_s, fea, fea_s, Wg, bg, Wf, bf, cand, GF, CF);
    knn_fused6<<<NQ / QPB, 512, 0, stream>>>(cand, xyz, idxb);
    fuse_kernel<<<NB * (NPTS / 16), 256, 0, stream>>>(
        xyz, Wg, cand, GF, CF, idxb, out);
}

// Round 20
// 181.697 us; speedup vs baseline: 1.0647x; 1.0647x over previous
//
#include <hip/hip_runtime.h>
#include <math.h>

#define NPTS 8192
#define NB   4
#define KNN  16
#define NC   64
#define NQ   (NB * NPTS)   // 32768 total queries
#define ECAP 20            // per-(wave,query) packed-entry capacity (E~2.7)
#define ILCAP 66           // per-query decoded survivor idx capacity (E~22)

// ---------------------------------------------------------------------------
// prep — unchanged (validated r18): 64-thread / 64-point blocks, grid 2048.
//  phase 0 (source pts): cand[b][m]=(x,y,z,|p|^2); GF[b][m][o]=(Gk,F2)
//  phase 1 (center pts): CF[b][n][o]=(Gc+bg, F1+bf)
// ---------------------------------------------------------------------------
__global__ __launch_bounds__(64) void prep_kernel(
    const float* __restrict__ xyz, const float* __restrict__ xyz_s,
    const float* __restrict__ fea, const float* __restrict__ fea_s,
    const float* __restrict__ Wg,  const float* __restrict__ bg,
    const float* __restrict__ Wf,  const float* __restrict__ bf,
    float4* __restrict__ cand, float2* __restrict__ GF, float2* __restrict__ CF)
{
    __shared__ float wt[64 * 64];
    __shared__ float gw[3 * 64];
    __shared__ float bias2[2 * 64];
    int tid   = threadIdx.x;
    int phase = blockIdx.x & 1;
    int g     = (blockIdx.x >> 1) * 64 + tid;
    int b     = g >> 13, m = g & (NPTS - 1);

    for (int i = tid; i < 4096; i += 64) {
        int o = i >> 6, c = i & 63;
        wt[c * 64 + o] = Wf[o * 128 + (phase ? c : 64 + c)];
    }
    for (int i = tid; i < 192; i += 64) {
        int d = i >> 6, o = i & 63;
        gw[d * 64 + o] = phase ? (Wg[o * 10 + 1 + d] + Wg[o * 10 + 7 + d])
                               : (Wg[o * 10 + 4 + d] - Wg[o * 10 + 7 + d]);
    }
    {
        bias2[tid]      = phase ? bg[tid] : 0.f;
        bias2[64 + tid] = phase ? bf[tid] : 0.f;
    }
    __syncthreads();

    const float* P = phase ? xyz : xyz_s;
    const float* F = phase ? fea : fea_s;
    float x = P[(b * 3 + 0) * NPTS + m];
    float y = P[(b * 3 + 1) * NPTS + m];
    float z = P[(b * 3 + 2) * NPTS + m];
    if (!phase) cand[b * NPTS + m] = make_float4(x, y, z, x * x + y * y + z * z);

    float acc[NC];
    #pragma unroll
    for (int o = 0; o < NC; o++) acc[o] = 0.f;
    for (int c = 0; c < NC; c++) {
        float v = F[(size_t)(b * NC + c) * NPTS + m];
        const float4* w4 = (const float4*)&wt[c * 64];
        #pragma unroll
        for (int o4 = 0; o4 < 16; o4++) {
            float4 w = w4[o4];
            acc[o4*4+0] = fmaf(w.x, v, acc[o4*4+0]);
            acc[o4*4+1] = fmaf(w.y, v, acc[o4*4+1]);
            acc[o4*4+2] = fmaf(w.z, v, acc[o4*4+2]);
            acc[o4*4+3] = fmaf(w.w, v, acc[o4*4+3]);
        }
    }
    float2* O = (phase ? CF : GF) + ((size_t)(b * NPTS + m)) * NC;
    #pragma unroll
    for (int o = 0; o < NC; o++) {
        float geo = fmaf(gw[o], x, fmaf(gw[64 + o], y, gw[128 + o] * z));
        O[o] = make_float2(geo + bias2[o], acc[o] + bias2[64 + o]);
    }
}

// ---------------------------------------------------------------------------
// knn_fused4 — EXACT r16/r18 revert (best measured: 106.5us).
// [r19 post-mortem: QPB=32 regressed (111.4us) — occupancy plateau ~31% is
//  NOT grid-limited (4 blocks/CU available, LDS/VGPR fine); it's the phase
//  structure (barrier-synced waves co-entering DS-latency regions). Doubling
//  blocks just doubled the per-block prologue. Reverted to QPB=64.]
// Wave w owns cands [1024w,1024(w+1)); lane owns c[s]=cb[w*1024+s*64+lane].
//  A: full 16-slot dual-chain lane max -> shfl_xor(1,2,4) -> 64 submaxima
//     (128-cand disjoint groups covering all 8192).
//  T: tau = 16th largest of 64 submaxima -> qt_lds[q].w; >=16 witnesses.
//  B: branch-free u16 mask filter (bit-identical fma), ONE ballot/query,
//     packed (lane<<16)|mask entries.
//  S: decode -> idx list (dead mxs row) -> batch-4 gather + u64 insert.
// Grid: NQ/64 = 512 blocks x 512 threads.
// ---------------------------------------------------------------------------
__global__ __launch_bounds__(512, 4) void knn_fused4(
    const float4* __restrict__ cand, const float* __restrict__ xyz,
    int* __restrict__ idxout)
{
    __shared__ float4 qt_lds[64];            // .w = tau after T
    __shared__ float  mxs[64][ILCAP];        // A/T: submaxima; S: idx list
    __shared__ unsigned int  el[8][64][ECAP];
    __shared__ unsigned char ecnt[8][64];

    int tid = threadIdx.x;
    int lane = tid & 63, w = tid >> 6;       // w in 0..7
    int bid = blockIdx.x;
    int b = bid >> 7;                        // 128 blocks per batch
    int qb = (bid & 127) * 64;

    if (tid < 64) {
        int q = qb + tid;
        float x = xyz[(b * 3 + 0) * NPTS + q];
        float y = xyz[(b * 3 + 1) * NPTS + q];
        float z = xyz[(b * 3 + 2) * NPTS + q];
        qt_lds[tid] = make_float4(2.f * x, 2.f * y, 2.f * z, 0.f);
    }

    const float4* cb = cand + b * NPTS;
    int cbase = (w << 10) + lane;            // lane's cands: cbase + s*64
    float4 c[16];
    #pragma unroll
    for (int s = 0; s < 16; s++) c[s] = cb[cbase + (s << 6)];
    // residency force (r15-validated): compiler cannot re-load from memory
    #pragma unroll
    for (int s = 0; s < 16; s++)
        asm volatile("" : "+v"(c[s].x), "+v"(c[s].y), "+v"(c[s].z), "+v"(c[s].w));
    __syncthreads();

    // ---- A: 64 submaxima per query (dual-chain lane max + 8-lane reduce) --
    for (int qi = 0; qi < 64; ++qi) {
        float4 qt = qt_lds[qi];
        float M0 = -3.0e38f, M1 = -3.0e38f;
        #pragma unroll
        for (int s = 0; s < 16; s += 2) {
            float sc0 = fmaf(c[s].x, qt.x, fmaf(c[s].y, qt.y,
                        fmaf(c[s].z, qt.z, -c[s].w)));
            float sc1 = fmaf(c[s+1].x, qt.x, fmaf(c[s+1].y, qt.y,
                        fmaf(c[s+1].z, qt.z, -c[s+1].w)));
            M0 = fmaxf(M0, sc0);
            M1 = fmaxf(M1, sc1);
        }
        float gmx = fmaxf(M0, M1);
        gmx = fmaxf(gmx, __shfl_xor(gmx, 1));
        gmx = fmaxf(gmx, __shfl_xor(gmx, 2));
        gmx = fmaxf(gmx, __shfl_xor(gmx, 4));   // 8-lane group max
        if ((lane & 7) == 0) mxs[qi][(w << 3) + (lane >> 3)] = gmx;
    }
    __syncthreads();

    // ---- T: tau = 16th largest of 64 submaxima -> qt_lds[qq].w ----
    for (int qq = w * 8; qq < w * 8 + 8; ++qq) {
        float v = mxs[qq][lane];
        #pragma unroll
        for (int k = 2; k <= 64; k <<= 1) {
            #pragma unroll
            for (int j = k >> 1; j > 0; j >>= 1) {
                float o = __shfl_xor(v, j);
                bool up = ((lane & k) == 0);
                bool lower = ((lane & j) == 0);
                v = (up == lower) ? fminf(v, o) : fmaxf(v, o);
            }
        }
        float t = __shfl(v, 48);             // 16th largest (all lanes)
        if (lane == 0) qt_lds[qq].w = t;
    }
    __syncthreads();

    // ---- B: branch-free mask filter; ONE ballot per (wave,query) ----
    unsigned long long lmask = (1ull << lane) - 1ull;
    for (int qi = 0; qi < 64; ++qi) {
        float4 qt = qt_lds[qi];              // .w = tau
        unsigned msk = 0;
        #pragma unroll
        for (int s = 0; s < 16; s++) {
            float sc = fmaf(c[s].x, qt.x, fmaf(c[s].y, qt.y,
                       fmaf(c[s].z, qt.z, -c[s].w)));
            msk |= (sc >= qt.w) ? (1u << s) : 0u;
        }
        unsigned long long m = __ballot(msk != 0u);
        if (msk) {
            unsigned pos = (unsigned)__popcll(m & lmask);
            if (pos < ECAP)
                el[w][qi][pos] = ((unsigned)lane << 16) | msk;
        }
        if (lane == 0) {
            unsigned tot = (unsigned)__popcll(m);
            ecnt[w][qi] = (unsigned char)(tot < ECAP ? tot : ECAP);
        }
    }
    __syncthreads();

    // ---- S: decode entries -> idx list (reuse mxs row), then top-16 ----
    if (tid < 64) {
        int qi = tid;
        unsigned* il = (unsigned*)&mxs[qi][0];   // ILCAP u32 slots
        int cnt = 0;
        for (int w2 = 0; w2 < 8; w2++) {
            int cn = ecnt[w2][qi];
            for (int j = 0; j < cn; j++) {
                unsigned e = el[w2][qi][j];
                int base = (w2 << 10) + (int)(e >> 16);
                unsigned mk = e & 0xFFFFu;
                while (mk) {
                    int s = __builtin_ctz(mk);
                    mk &= mk - 1u;
                    if (cnt < ILCAP) il[cnt++] = (unsigned)(base + (s << 6));
                }
            }
        }

        float4 qt = qt_lds[qi];
        unsigned long long s16[KNN];
        #pragma unroll
        for (int j = 0; j < KNN; j++) s16[j] = 0ull;

        for (int j0 = 0; j0 < cnt; j0 += 4) {
            int li[4];
            float4 cd[4];
            #pragma unroll
            for (int t = 0; t < 4; t++) {
                int j = j0 + t;
                li[t] = (j < cnt) ? (int)il[j] : -1;
            }
            #pragma unroll
            for (int t = 0; t < 4; t++)
                if (li[t] >= 0) cd[t] = cb[li[t]];
            #pragma unroll
            for (int t = 0; t < 4; t++) {
                if (li[t] < 0) continue;
                float sc = fmaf(cd[t].x, qt.x, fmaf(cd[t].y, qt.y,
                           fmaf(cd[t].z, qt.z, -cd[t].w)));
                unsigned u = __float_as_uint(sc);
                u ^= (unsigned)((int)u >> 31) | 0x80000000u;
                unsigned long long key =
                    ((unsigned long long)u << 32) | (unsigned)(8191 - li[t]);
                if (key > s16[0]) {
                    bool cj = true;
                    #pragma unroll
                    for (int t2 = 0; t2 < KNN; t2++) {
                        bool cn2 = (t2 < KNN - 1) ? (key > s16[t2 + 1]) : false;
                        unsigned long long fv = cj ? key : s16[t2];
                        s16[t2] = cn2 ? s16[t2 + 1] : fv;
                        cj = cn2;
                    }
                }
            }
        }
        int* op = idxout + (((size_t)(b * NPTS + qb + qi)) << 4);
        #pragma unroll
        for (int j = 0; j < KNN; j++)
            op[j] = 8191 - (int)(s16[j] & 0xFFFFFFFFull);
    }
}

// ---------------------------------------------------------------------------
// fuse — r20: explicit register-batch loads (the r10/r15-validated pattern).
// [fuse measured ~40us vs ~12-15us floor (335M VALU ops ~8.5us; 268MB of
//  L2-resident GF reads ~8us) — gather-latency-bound: unroll-4 left <=8
//  loads in flight with dependent use. Now: load all 16 neighbor idx
//  (broadcast), then per half-batch of 8 load 8 cand float4 + 8 GF float2
//  into register arrays BEFORE any compute — 16 loads per wait.]
// out[b][o][n] = max_k relu(CF.x + wd*d + GF.x) * relu(CF.y + GF.y)
// ---------------------------------------------------------------------------
__global__ __launch_bounds__(256) void fuse_kernel(
    const float* __restrict__ xyz, const float* __restrict__ Wg,
    const float4* __restrict__ cand, const float2* __restrict__ GF,
    const float2* __restrict__ CF, const int* __restrict__ idxb,
    float* __restrict__ out)
{
    __shared__ float tile[16 * 65];
    int tid = threadIdx.x;
    int o = tid & 63, w = tid >> 6;
    int b = blockIdx.x >> 9;
    int nt = (blockIdx.x & 511) << 4;
    float wd = Wg[o * 10];

    const float4* cb = cand + b * NPTS;
    const float2* gb = GF + (size_t)b * NPTS * NC;

    for (int i = 0; i < 4; i++) {
        int q = nt + w * 4 + i;
        size_t qb = (size_t)(b * NPTS + q);
        float qx = xyz[(b * 3 + 0) * NPTS + q];
        float qy = xyz[(b * 3 + 1) * NPTS + q];
        float qz = xyz[(b * 3 + 2) * NPTS + q];
        float2 cf = CF[qb * NC + o];
        const int* ip = idxb + qb * KNN;

        int mi[16];
        #pragma unroll
        for (int kk = 0; kk < 16; kk++) mi[kk] = ip[kk];   // broadcast loads

        float r = 0.f;
        #pragma unroll
        for (int h = 0; h < 2; h++) {
            float4 cd[8];
            float2 gf[8];
            #pragma unroll
            for (int t = 0; t < 8; t++) cd[t] = cb[mi[h * 8 + t]];
            #pragma unroll
            for (int t = 0; t < 8; t++)
                gf[t] = gb[(size_t)mi[h * 8 + t] * NC + o];
            #pragma unroll
            for (int t = 0; t < 8; t++) {
                float dx = qx - cd[t].x, dy = qy - cd[t].y, dz = qz - cd[t].z;
                float d = sqrtf(fmaf(dx, dx, fmaf(dy, dy, dz * dz)));
                float gpre = cf.x + fmaf(wd, d, gf[t].x);
                float fpre = cf.y + gf[t].y;
                r = fmaxf(r, fmaxf(gpre, 0.f) * fmaxf(fpre, 0.f));
            }
        }
        tile[(w * 4 + i) * 65 + o] = r;
    }
    __syncthreads();
    int row = tid >> 2, cg = (tid & 3) * 4;
    float* orow = out + (size_t)(b * NC + row) * NPTS + nt + cg;
    #pragma unroll
    for (int j = 0; j < 4; j++) orow[j] = tile[(cg + j) * 65 + row];
}

extern "C" void kernel_launch(void* const* d_in, const int* in_sizes, int n_in,
                              void* d_out, int out_size, void* d_ws, size_t ws_size,
                              hipStream_t stream) {
    const float* xyz   = (const float*)d_in[0];
    const float* xyz_s = (const float*)d_in[1];
    const float* fea   = (const float*)d_in[2];
    const float* fea_s = (const float*)d_in[3];
    const float* Wg    = (const float*)d_in[4];
    const float* bg    = (const float*)d_in[5];
    const float* Wf    = (const float*)d_in[6];
    const float* bf    = (const float*)d_in[7];
    float* out = (float*)d_out;

    char* ws = (char*)d_ws;
    float4* cand = (float4*)ws;                 ws += (size_t)NQ * 16;      // 512 KB
    float2* GF   = (float2*)ws;                 ws += (size_t)NQ * NC * 8;  // 16.8 MB
    float2* CF   = (float2*)ws;                 ws += (size_t)NQ * NC * 8;  // 16.8 MB
    int*    idxb = (int*)ws;                                                // 2 MB

    // prep: 64-point / 64-thread blocks -> 2048 blocks = 8 blocks/CU
    prep_kernel<<<(NQ / 64) * 2, 64, 0, stream>>>(
        xyz, xyz_s, fea, fea_s, Wg, bg, Wf, bf, cand, GF, CF);
    knn_fused4<<<NQ / 64, 512, 0, stream>>>(cand, xyz, idxb);
    fuse_kernel<<<NB * (NPTS / 16), 256, 0, stream>>>(
        xyz, Wg, cand, GF, CF, idxb, out);
}

// Round 21
// 178.874 us; speedup vs baseline: 1.0816x; 1.0158x over previous
//
#include <hip/hip_runtime.h>
#include <math.h>

#define NPTS 8192
#define NB   4
#define KNN  16
#define NC   64
#define NQ   (NB * NPTS)   // 32768 total queries
#define ECAP 20            // per-(wave,query) packed-entry capacity (E~2.7)
#define ILCAP 66           // per-query decoded survivor idx capacity (E~22)

// ---------------------------------------------------------------------------
// prep — r21 TRANSPOSED OWNERSHIP: lane = output channel o (NC==wavesize).
// [r20 post-mortem: prep was LDS-pipe-bound — point-per-thread forced 1024
//  broadcast ds_read_b128/wave for weights. Transposing makes weights
//  per-lane L1 reads (Wf row o is private), fea reads WAVE-UNIFORM (no
//  threadIdx in address -> s_load on the scalar pipe), stores coalesced
//  (lanes o=0..63 write 64 consecutive float2 per point). Zero LDS.
//  Accumulation order per (m,o) identical -> outputs bit-identical.]
//  phase 0 (source pts): cand[b][m]=(x,y,z,|p|^2); GF[b][m][o]=(Gk,F2)
//  phase 1 (center pts): CF[b][n][o]=(Gc+bg, F1+bf)
// Block = 64 threads = 1 wave, 64 points; grid = (NQ/64)*2.
// ---------------------------------------------------------------------------
__global__ __launch_bounds__(64) void prep_kernel(
    const float* __restrict__ xyz, const float* __restrict__ xyz_s,
    const float* __restrict__ fea, const float* __restrict__ fea_s,
    const float* __restrict__ Wg,  const float* __restrict__ bg,
    const float* __restrict__ Wf,  const float* __restrict__ bf,
    float4* __restrict__ cand, float2* __restrict__ GF, float2* __restrict__ CF)
{
    int o     = threadIdx.x;                 // this lane's output channel
    int phase = blockIdx.x & 1;
    int g     = (blockIdx.x >> 1) * 64;      // first point of tile
    int b     = g >> 13, p0 = g & (NPTS - 1);

    const float* P = phase ? xyz : xyz_s;
    const float* F = phase ? fea : fea_s;

    if (!phase) {
        // lane l emits cand for point p0+l (coalesced loads/stores)
        float x = xyz_s[(b * 3 + 0) * NPTS + p0 + o];
        float y = xyz_s[(b * 3 + 1) * NPTS + p0 + o];
        float z = xyz_s[(b * 3 + 2) * NPTS + p0 + o];
        cand[b * NPTS + p0 + o] = make_float4(x, y, z, x * x + y * y + z * z);
    }

    // per-lane weight row (transposed ownership); L1-resident after 1st tile
    const float* wrow = Wf + o * 128 + (phase ? 0 : 64);
    float gwx = phase ? (Wg[o * 10 + 1] + Wg[o * 10 + 7])
                      : (Wg[o * 10 + 4] - Wg[o * 10 + 7]);
    float gwy = phase ? (Wg[o * 10 + 2] + Wg[o * 10 + 8])
                      : (Wg[o * 10 + 5] - Wg[o * 10 + 8]);
    float gwz = phase ? (Wg[o * 10 + 3] + Wg[o * 10 + 9])
                      : (Wg[o * 10 + 6] - Wg[o * 10 + 9]);
    float bgo = phase ? bg[o] : 0.f;
    float bfo = phase ? bf[o] : 0.f;

    float acc[64];
    #pragma unroll
    for (int p = 0; p < 64; p++) acc[p] = 0.f;

    for (int c = 0; c < 64; c++) {
        float wv = wrow[c];                           // per-lane L1 read
        const float4* fr =
            (const float4*)(F + (size_t)(b * NC + c) * NPTS + p0);
        #pragma unroll
        for (int p4 = 0; p4 < 16; p4++) {
            float4 v = fr[p4];                        // wave-uniform -> s_load
            acc[p4 * 4 + 0] = fmaf(wv, v.x, acc[p4 * 4 + 0]);
            acc[p4 * 4 + 1] = fmaf(wv, v.y, acc[p4 * 4 + 1]);
            acc[p4 * 4 + 2] = fmaf(wv, v.z, acc[p4 * 4 + 2]);
            acc[p4 * 4 + 3] = fmaf(wv, v.w, acc[p4 * 4 + 3]);
        }
    }

    float2* O = (phase ? CF : GF) + ((size_t)(b * NPTS + p0)) * NC + o;
    for (int p = 0; p < 64; p++) {
        float x = P[(b * 3 + 0) * NPTS + p0 + p];     // uniform -> s_load
        float y = P[(b * 3 + 1) * NPTS + p0 + p];
        float z = P[(b * 3 + 2) * NPTS + p0 + p];
        float geo = fmaf(gwx, x, fmaf(gwy, y, gwz * z)) + bgo;
        O[(size_t)p * NC] = make_float2(geo, acc[p] + bfo);  // coalesced
    }
}

// ---------------------------------------------------------------------------
// knn_fused4 — unchanged (r16/r18/r20 validated, 106.5us).
// Wave w owns cands [1024w,1024(w+1)); lane owns c[s]=cb[w*1024+s*64+lane].
//  A: full 16-slot dual-chain lane max -> shfl_xor(1,2,4) -> 64 submaxima
//     (128-cand disjoint groups covering all 8192).
//  T: tau = 16th largest of 64 submaxima -> qt_lds[q].w; >=16 witnesses.
//  B: branch-free u16 mask filter (bit-identical fma), ONE ballot/query,
//     packed (lane<<16)|mask entries.
//  S: decode -> idx list (dead mxs row) -> batch-4 gather + u64 insert.
// Grid: NQ/64 = 512 blocks x 512 threads.
// ---------------------------------------------------------------------------
__global__ __launch_bounds__(512, 4) void knn_fused4(
    const float4* __restrict__ cand, const float* __restrict__ xyz,
    int* __restrict__ idxout)
{
    __shared__ float4 qt_lds[64];            // .w = tau after T
    __shared__ float  mxs[64][ILCAP];        // A/T: submaxima; S: idx list
    __shared__ unsigned int  el[8][64][ECAP];
    __shared__ unsigned char ecnt[8][64];

    int tid = threadIdx.x;
    int lane = tid & 63, w = tid >> 6;       // w in 0..7
    int bid = blockIdx.x;
    int b = bid >> 7;                        // 128 blocks per batch
    int qb = (bid & 127) * 64;

    if (tid < 64) {
        int q = qb + tid;
        float x = xyz[(b * 3 + 0) * NPTS + q];
        float y = xyz[(b * 3 + 1) * NPTS + q];
        float z = xyz[(b * 3 + 2) * NPTS + q];
        qt_lds[tid] = make_float4(2.f * x, 2.f * y, 2.f * z, 0.f);
    }

    const float4* cb = cand + b * NPTS;
    int cbase = (w << 10) + lane;            // lane's cands: cbase + s*64
    float4 c[16];
    #pragma unroll
    for (int s = 0; s < 16; s++) c[s] = cb[cbase + (s << 6)];
    // residency force (r15-validated): compiler cannot re-load from memory
    #pragma unroll
    for (int s = 0; s < 16; s++)
        asm volatile("" : "+v"(c[s].x), "+v"(c[s].y), "+v"(c[s].z), "+v"(c[s].w));
    __syncthreads();

    // ---- A: 64 submaxima per query (dual-chain lane max + 8-lane reduce) --
    for (int qi = 0; qi < 64; ++qi) {
        float4 qt = qt_lds[qi];
        float M0 = -3.0e38f, M1 = -3.0e38f;
        #pragma unroll
        for (int s = 0; s < 16; s += 2) {
            float sc0 = fmaf(c[s].x, qt.x, fmaf(c[s].y, qt.y,
                        fmaf(c[s].z, qt.z, -c[s].w)));
            float sc1 = fmaf(c[s+1].x, qt.x, fmaf(c[s+1].y, qt.y,
                        fmaf(c[s+1].z, qt.z, -c[s+1].w)));
            M0 = fmaxf(M0, sc0);
            M1 = fmaxf(M1, sc1);
        }
        float gmx = fmaxf(M0, M1);
        gmx = fmaxf(gmx, __shfl_xor(gmx, 1));
        gmx = fmaxf(gmx, __shfl_xor(gmx, 2));
        gmx = fmaxf(gmx, __shfl_xor(gmx, 4));   // 8-lane group max
        if ((lane & 7) == 0) mxs[qi][(w << 3) + (lane >> 3)] = gmx;
    }
    __syncthreads();

    // ---- T: tau = 16th largest of 64 submaxima -> qt_lds[qq].w ----
    for (int qq = w * 8; qq < w * 8 + 8; ++qq) {
        float v = mxs[qq][lane];
        #pragma unroll
        for (int k = 2; k <= 64; k <<= 1) {
            #pragma unroll
            for (int j = k >> 1; j > 0; j >>= 1) {
                float o = __shfl_xor(v, j);
                bool up = ((lane & k) == 0);
                bool lower = ((lane & j) == 0);
                v = (up == lower) ? fminf(v, o) : fmaxf(v, o);
            }
        }
        float t = __shfl(v, 48);             // 16th largest (all lanes)
        if (lane == 0) qt_lds[qq].w = t;
    }
    __syncthreads();

    // ---- B: branch-free mask filter; ONE ballot per (wave,query) ----
    unsigned long long lmask = (1ull << lane) - 1ull;
    for (int qi = 0; qi < 64; ++qi) {
        float4 qt = qt_lds[qi];              // .w = tau
        unsigned msk = 0;
        #pragma unroll
        for (int s = 0; s < 16; s++) {
            float sc = fmaf(c[s].x, qt.x, fmaf(c[s].y, qt.y,
                       fmaf(c[s].z, qt.z, -c[s].w)));
            msk |= (sc >= qt.w) ? (1u << s) : 0u;
        }
        unsigned long long m = __ballot(msk != 0u);
        if (msk) {
            unsigned pos = (unsigned)__popcll(m & lmask);
            if (pos < ECAP)
                el[w][qi][pos] = ((unsigned)lane << 16) | msk;
        }
        if (lane == 0) {
            unsigned tot = (unsigned)__popcll(m);
            ecnt[w][qi] = (unsigned char)(tot < ECAP ? tot : ECAP);
        }
    }
    __syncthreads();

    // ---- S: decode entries -> idx list (reuse mxs row), then top-16 ----
    if (tid < 64) {
        int qi = tid;
        unsigned* il = (unsigned*)&mxs[qi][0];   // ILCAP u32 slots
        int cnt = 0;
        for (int w2 = 0; w2 < 8; w2++) {
            int cn = ecnt[w2][qi];
            for (int j = 0; j < cn; j++) {
                unsigned e = el[w2][qi][j];
                int base = (w2 << 10) + (int)(e >> 16);
                unsigned mk = e & 0xFFFFu;
                while (mk) {
                    int s = __builtin_ctz(mk);
                    mk &= mk - 1u;
                    if (cnt < ILCAP) il[cnt++] = (unsigned)(base + (s << 6));
                }
            }
        }

        float4 qt = qt_lds[qi];
        unsigned long long s16[KNN];
        #pragma unroll
        for (int j = 0; j < KNN; j++) s16[j] = 0ull;

        for (int j0 = 0; j0 < cnt; j0 += 4) {
            int li[4];
            float4 cd[4];
            #pragma unroll
            for (int t = 0; t < 4; t++) {
                int j = j0 + t;
                li[t] = (j < cnt) ? (int)il[j] : -1;
            }
            #pragma unroll
            for (int t = 0; t < 4; t++)
                if (li[t] >= 0) cd[t] = cb[li[t]];
            #pragma unroll
            for (int t = 0; t < 4; t++) {
                if (li[t] < 0) continue;
                float sc = fmaf(cd[t].x, qt.x, fmaf(cd[t].y, qt.y,
                           fmaf(cd[t].z, qt.z, -cd[t].w)));
                unsigned u = __float_as_uint(sc);
                u ^= (unsigned)((int)u >> 31) | 0x80000000u;
                unsigned long long key =
                    ((unsigned long long)u << 32) | (unsigned)(8191 - li[t]);
                if (key > s16[0]) {
                    bool cj = true;
                    #pragma unroll
                    for (int t2 = 0; t2 < KNN; t2++) {
                        bool cn2 = (t2 < KNN - 1) ? (key > s16[t2 + 1]) : false;
                        unsigned long long fv = cj ? key : s16[t2];
                        s16[t2] = cn2 ? s16[t2 + 1] : fv;
                        cj = cn2;
                    }
                }
            }
        }
        int* op = idxout + (((size_t)(b * NPTS + qb + qi)) << 4);
        #pragma unroll
        for (int j = 0; j < KNN; j++)
            op[j] = 8191 - (int)(s16[j] & 0xFFFFFFFFull);
    }
}

// ---------------------------------------------------------------------------
// fuse — unchanged (r20 validated): explicit register-batch gathers.
// out[b][o][n] = max_k relu(CF.x + wd*d + GF.x) * relu(CF.y + GF.y)
// ---------------------------------------------------------------------------
__global__ __launch_bounds__(256) void fuse_kernel(
    const float* __restrict__ xyz, const float* __restrict__ Wg,
    const float4* __restrict__ cand, const float2* __restrict__ GF,
    const float2* __restrict__ CF, const int* __restrict__ idxb,
    float* __restrict__ out)
{
    __shared__ float tile[16 * 65];
    int tid = threadIdx.x;
    int o = tid & 63, w = tid >> 6;
    int b = blockIdx.x >> 9;
    int nt = (blockIdx.x & 511) << 4;
    float wd = Wg[o * 10];

    const float4* cb = cand + b * NPTS;
    const float2* gb = GF + (size_t)b * NPTS * NC;

    for (int i = 0; i < 4; i++) {
        int q = nt + w * 4 + i;
        size_t qb = (size_t)(b * NPTS + q);
        float qx = xyz[(b * 3 + 0) * NPTS + q];
        float qy = xyz[(b * 3 + 1) * NPTS + q];
        float qz = xyz[(b * 3 + 2) * NPTS + q];
        float2 cf = CF[qb * NC + o];
        const int* ip = idxb + qb * KNN;

        int mi[16];
        #pragma unroll
        for (int kk = 0; kk < 16; kk++) mi[kk] = ip[kk];   // broadcast loads

        float r = 0.f;
        #pragma unroll
        for (int h = 0; h < 2; h++) {
            float4 cd[8];
            float2 gf[8];
            #pragma unroll
            for (int t = 0; t < 8; t++) cd[t] = cb[mi[h * 8 + t]];
            #pragma unroll
            for (int t = 0; t < 8; t++)
                gf[t] = gb[(size_t)mi[h * 8 + t] * NC + o];
            #pragma unroll
            for (int t = 0; t < 8; t++) {
                float dx = qx - cd[t].x, dy = qy - cd[t].y, dz = qz - cd[t].z;
                float d = sqrtf(fmaf(dx, dx, fmaf(dy, dy, dz * dz)));
                float gpre = cf.x + fmaf(wd, d, gf[t].x);
                float fpre = cf.y + gf[t].y;
                r = fmaxf(r, fmaxf(gpre, 0.f) * fmaxf(fpre, 0.f));
            }
        }
        tile[(w * 4 + i) * 65 + o] = r;
    }
    __syncthreads();
    int row = tid >> 2, cg = (tid & 3) * 4;
    float* orow = out + (size_t)(b * NC + row) * NPTS + nt + cg;
    #pragma unroll
    for (int j = 0; j < 4; j++) orow[j] = tile[(cg + j) * 65 + row];
}

extern "C" void kernel_launch(void* const* d_in, const int* in_sizes, int n_in,
                              void* d_out, int out_size, void* d_ws, size_t ws_size,
                              hipStream_t stream) {
    const float* xyz   = (const float*)d_in[0];
    const float* xyz_s = (const float*)d_in[1];
    const float* fea   = (const float*)d_in[2];
    const float* fea_s = (const float*)d_in[3];
    const float* Wg    = (const float*)d_in[4];
    const float* bg    = (const float*)d_in[5];
    const float* Wf    = (const float*)d_in[6];
    const float* bf    = (const float*)d_in[7];
    float* out = (float*)d_out;

    char* ws = (char*)d_ws;
    float4* cand = (float4*)ws;                 ws += (size_t)NQ * 16;      // 512 KB
    float2* GF   = (float2*)ws;                 ws += (size_t)NQ * NC * 8;  // 16.8 MB
    float2* CF   = (float2*)ws;                 ws += (size_t)NQ * NC * 8;  // 16.8 MB
    int*    idxb = (int*)ws;                                                // 2 MB

    // prep: transposed ownership, 64 points / 64 threads, 2 phases
    prep_kernel<<<(NQ / 64) * 2, 64, 0, stream>>>(
        xyz, xyz_s, fea, fea_s, Wg, bg, Wf, bf, cand, GF, CF);
    knn_fused4<<<NQ / 64, 512, 0, stream>>>(cand, xyz, idxb);
    fuse_kernel<<<NB * (NPTS / 16), 256, 0, stream>>>(
        xyz, Wg, cand, GF, CF, idxb, out);
}